// Round 1
// baseline (392.348 us; speedup 1.0000x reference)
//
#include <hip/hip_runtime.h>
#include <math.h>

// GRNN Kalman scan: B=512 independent chains, T=4096 sequential steps each.
// Round 0: one thread per batch element, all state in registers.
// Key algebra (C = c*[[1,0],[0,0]], c^2 = 4*eta*kappa = 2.88):
//   xicov = [[c*vx, 0], [c*cxp, 0]]  -> dy[:,:,1] unused, dy_hat[:,:,1] == 0
//   M = [[a - c2*vx, w], [-w - c2*cxp, a]],  a = -gamma/2 = -0.15
//   dvx  = DT*(2a*vx + 2w*cxp + Dd - c2*vx^2)
//   dvp  = DT*(2a*vp - 2w*cxp + Dd - c2*cxp^2)
//   dcxp = DT*(2a*cxp + w*(vp - vx) - c2*vx*cxp)
//   Dd = gamma*(nbar+0.5)+kappa = 1.65

constexpr int T = 4096;
constexpr int B = 512;

__global__ __launch_bounds__(64) void grnn_step_kernel(
    const float* __restrict__ dy,
    const float* __restrict__ state0,
    const float* __restrict__ omega_p,
    float* __restrict__ out)
{
    const int b = blockIdx.x * 64 + threadIdx.x;
    if (b >= B) return;

    const float DT  = 0.001f;
    const float a   = -0.15f;        // -0.5*GAMMA
    const float c2  = 2.88f;         // 4*ETA*KAPPA
    const float cc  = 1.69705627f;   // sqrt(2.88)
    const float Dd  = 1.65f;         // GAMMA*(NBAR+0.5)+KAPPA
    const float w   = omega_p[0];
    const float a2  = -0.3f;         // 2a
    const float w2  = 2.0f * w;
    const float kcDT = cc * DT;

    const float* sp = state0 + b * 6;
    float x0 = sp[0], x1 = sp[1], vx = sp[2], vp = sp[3], cxp = sp[4], t = sp[5];

    const float* __restrict__ dyb = dy + (size_t)b * (T * 2);
    float* __restrict__ dyh = out + B * 6 + (size_t)b * (T * 2);

    for (int tt = 0; tt < T; tt += 4) {
        const float4 d0 = *(const float4*)(dyb + tt * 2);
        const float4 d1 = *(const float4*)(dyb + tt * 2 + 4);
        const float dyv[4] = {d0.x, d0.z, d1.x, d1.z};
        float hv[4];
        #pragma unroll
        for (int k = 0; k < 4; ++k) {
            const float dy0 = dyv[k];
            hv[k] = kcDT * x0;                 // dy_hat uses pre-update x0
            // x update: x' = x + DT*(M@x) + xicov[:,0]*dy0
            const float M00 = fmaf(-c2, vx, a);
            const float M10 = fmaf(-c2, cxp, -w);
            const float g0  = cc * vx;
            const float g1  = cc * cxp;
            const float x0n = fmaf(fmaf(M00, x0, w * x1), DT, fmaf(g0, dy0, x0));
            const float x1n = fmaf(fmaf(M10, x0, a * x1), DT, fmaf(g1, dy0, x1));
            // cov update (batch-independent Riccati, done redundantly per lane)
            const float nvx = -c2 * vx;
            const float ncx = -c2 * cxp;
            float ux = fmaf(nvx, vx, Dd);
            ux = fmaf(w2, cxp, ux);
            ux = fmaf(a2, vx, ux);
            float up = fmaf(ncx, cxp, Dd);
            up = fmaf(-w2, cxp, up);
            up = fmaf(a2, vp, up);
            float uc = w * (vp - vx);
            uc = fmaf(a2, cxp, uc);
            uc = fmaf(nvx, cxp, uc);
            vx  = fmaf(DT, ux, vx);
            vp  = fmaf(DT, up, vp);
            cxp = fmaf(DT, uc, cxp);
            x0 = x0n; x1 = x1n;
            t += DT;
        }
        *(float4*)(dyh + tt * 2)     = make_float4(hv[0], 0.0f, hv[1], 0.0f);
        *(float4*)(dyh + tt * 2 + 4) = make_float4(hv[2], 0.0f, hv[3], 0.0f);
    }

    float* os = out + b * 6;
    os[0] = x0; os[1] = x1; os[2] = vx; os[3] = vp; os[4] = cxp; os[5] = t;
}

extern "C" void kernel_launch(void* const* d_in, const int* in_sizes, int n_in,
                              void* d_out, int out_size, void* d_ws, size_t ws_size,
                              hipStream_t stream) {
    const float* dy     = (const float*)d_in[0];
    const float* state0 = (const float*)d_in[1];
    const float* omega  = (const float*)d_in[2];
    float* out = (float*)d_out;
    grnn_step_kernel<<<B / 64, 64, 0, stream>>>(dy, state0, omega, out);
}

// Round 2
// 204.030 us; speedup vs baseline: 1.9230x; 1.9230x over previous
//
#include <hip/hip_runtime.h>
#include <math.h>

// GRNN Kalman scan, chunked-affine-scan rewrite.
// Facts: cov Riccati is batch-independent; x-recursion is affine:
//   x_{t+1} = T_t x_t + g_t * dy[b,t,0]
//   T_t = [[kA - k4*vx_t, kw], [-kw - k4*cxp_t, kA]], g_t = cc*(vx_t, cxp_t)
//   kA = 1+DT*a (a=-0.15), kw = DT*w, k4 = DT*c2 (c2=2.88), cc = sqrt(2.88)
// dy[:,:,1] never enters (C column 1 = 0); dy_hat[:,:,1] == 0.
//
// Kernel 1 (1 block, 64 threads):
//   lane 0: serial Riccati, store (vx,cxp) per t in LDS, final cov+t to ws.
//   all lanes: per-chunk backward pass -> Ttab {T00,T10,g0,g1}, Htab = R*g,
//   Ptab = chunk product.
// Kernel 2 (512 blocks = batches, 64 lanes = chunks of 64 steps):
//   B: q_c = sum_t Htab_t * dy0   (reduction, 2 FMA/step)
//   C: wave Hillis-Steele scan composing (P,q) -> x at chunk starts
//   D: re-walk 64 steps with Ttab, write dy_hat; lane 63 writes final state.

constexpr int T = 4096;
constexpr int B = 512;
constexpr int CH = 64;      // steps per chunk
constexpr int NC = T / CH;  // 64 chunks

// ws layout (float offsets):
//   [0, 16384)      Ttab  float4[T]  {T00, T10, g0, g1}
//   [16384, 24576)  Htab  float2[T]  {h0, h1}
//   [24576, 24832)  Ptab  float4[NC] {p00, p01, p10, p11}
//   [24832, 24836)  fin   float4     {vx_f, vp_f, cxp_f, t_f}
constexpr int WS_T = 0;
constexpr int WS_H = 16384;
constexpr int WS_P = 24576;
constexpr int WS_F = 24832;

__global__ __launch_bounds__(64) void grnn_phaseA(
    const float* __restrict__ state0,
    const float* __restrict__ omega_p,
    float* __restrict__ ws)
{
    __shared__ float2 scov[T];  // 32 KB: (vx_t, cxp_t) pre-update
    const int lane = threadIdx.x;

    const float DT = 0.001f;
    const float w  = omega_p[0];
    const float k1 = 1.0f + DT * (-0.3f);   // 1 + DT*2a
    const float k2 = DT * 2.0f * w;
    const float k3 = DT * 1.65f;            // DT*Dd
    const float k4 = DT * 2.88f;            // DT*c2
    const float kw = DT * w;
    const float kA = 1.0f + DT * (-0.15f);  // 1 + DT*a
    const float cc = 1.69705627484771f;     // sqrt(2.88)

    if (lane == 0) {
        float vx = state0[2], vp = state0[3], cxp = state0[4], t = state0[5];
        #pragma unroll 8
        for (int tt = 0; tt < T; ++tt) {
            scov[tt] = make_float2(vx, cxp);
            const float t1  = fmaf(-k4, vx, k1);          // shared linear coeff
            const float s1  = fmaf(k2, cxp, k3);
            const float m   = kw * (vp - vx);
            const float in1 = fmaf(-k4, cxp, -k2);
            const float in2 = fmaf(in1, cxp, k3);
            const float nvx = fmaf(t1, vx, s1);
            const float ncx = fmaf(t1, cxp, m);
            const float nvp = fmaf(k1, vp, in2);
            vx = nvx; cxp = ncx; vp = nvp;
            t += DT;   // replicate reference's sequential fp32 accumulation
        }
        *(float4*)(ws + WS_F) = make_float4(vx, vp, cxp, t);
    }
    __syncthreads();

    // Backward pass over this lane's chunk: H_t = R * g_t, R <- R * T_t.
    float r00 = 1.f, r01 = 0.f, r10 = 0.f, r11 = 1.f;
    const int c = lane;
    float4* Ttab = (float4*)(ws + WS_T);
    float2* Htab = (float2*)(ws + WS_H);
    #pragma unroll 4
    for (int j = CH - 1; j >= 0; --j) {
        const int t = c * CH + j;
        const float2 vc = scov[t];
        const float T00 = fmaf(-k4, vc.x, kA);
        const float T10 = fmaf(-k4, vc.y, -kw);
        const float g0  = cc * vc.x;
        const float g1  = cc * vc.y;
        Htab[t] = make_float2(fmaf(r00, g0, r01 * g1), fmaf(r10, g0, r11 * g1));
        Ttab[t] = make_float4(T00, T10, g0, g1);
        const float n00 = fmaf(r00, T00, r01 * T10);
        const float n01 = fmaf(r00, kw,  r01 * kA);
        const float n10 = fmaf(r10, T00, r11 * T10);
        const float n11 = fmaf(r10, kw,  r11 * kA);
        r00 = n00; r01 = n01; r10 = n10; r11 = n11;
    }
    ((float4*)(ws + WS_P))[c] = make_float4(r00, r01, r10, r11);
}

__global__ __launch_bounds__(64) void grnn_phaseBCD(
    const float* __restrict__ dy,
    const float* __restrict__ state0,
    const float* __restrict__ omega_p,
    float* __restrict__ out,
    const float* __restrict__ ws)
{
    const int b = blockIdx.x;
    const int c = threadIdx.x;   // chunk index == lane

    const float DT = 0.001f;
    const float w  = omega_p[0];
    const float kw = DT * w;
    const float kA = 1.0f + DT * (-0.15f);
    const float cc = 1.69705627484771f;
    const float kcDT = cc * DT;

    const float4* Ttab = (const float4*)(ws + WS_T);
    const float4* H4   = (const float4*)(ws + WS_H);  // 2 timesteps per float4

    // ---- Phase B: q_c = sum_t H_t * dy0 ----
    const float* dyb = dy + (size_t)b * (T * 2) + c * (CH * 2);
    float q0 = 0.f, q1 = 0.f;
    #pragma unroll 8
    for (int j = 0; j < CH; j += 2) {
        const float4 d = *(const float4*)(dyb + j * 2);
        const float4 h = H4[(c * CH + j) >> 1];
        q0 = fmaf(h.x, d.x, q0);
        q1 = fmaf(h.y, d.x, q1);
        q0 = fmaf(h.z, d.z, q0);
        q1 = fmaf(h.w, d.z, q1);
    }
    const float4 Pv = ((const float4*)(ws + WS_P))[c];
    float p00 = Pv.x, p01 = Pv.y, p10 = Pv.z, p11 = Pv.w;

    // ---- Phase C: inclusive Hillis-Steele scan of affine maps (P,q) ----
    // compose: self AFTER other: P = P_self*P_oth, q = P_self*q_oth + q_self
    for (int d = 1; d < 64; d <<= 1) {
        const float o00 = __shfl_up(p00, d), o01 = __shfl_up(p01, d);
        const float o10 = __shfl_up(p10, d), o11 = __shfl_up(p11, d);
        const float oq0 = __shfl_up(q0, d),  oq1 = __shfl_up(q1, d);
        if (c >= d) {
            const float n00 = fmaf(p00, o00, p01 * o10);
            const float n01 = fmaf(p00, o01, p01 * o11);
            const float n10 = fmaf(p10, o00, p11 * o10);
            const float n11 = fmaf(p10, o01, p11 * o11);
            const float nq0 = fmaf(p00, oq0, fmaf(p01, oq1, q0));
            const float nq1 = fmaf(p10, oq0, fmaf(p11, oq1, q1));
            p00 = n00; p01 = n01; p10 = n10; p11 = n11;
            q0 = nq0; q1 = nq1;
        }
    }
    // exclusive shift: lane c gets inclusive prefix of lane c-1; lane 0 identity
    float e00 = __shfl_up(p00, 1), e01 = __shfl_up(p01, 1);
    float e10 = __shfl_up(p10, 1), e11 = __shfl_up(p11, 1);
    float eq0 = __shfl_up(q0, 1),  eq1 = __shfl_up(q1, 1);
    if (c == 0) { e00 = 1.f; e01 = 0.f; e10 = 0.f; e11 = 1.f; eq0 = 0.f; eq1 = 0.f; }

    const float xi0 = state0[b * 6 + 0];
    const float xi1 = state0[b * 6 + 1];
    float x0 = fmaf(e00, xi0, fmaf(e01, xi1, eq0));
    float x1 = fmaf(e10, xi0, fmaf(e11, xi1, eq1));

    // ---- Phase D: re-walk chunk, write dy_hat (pre-update x each step) ----
    float* dyh = out + B * 6 + (size_t)b * (T * 2) + c * (CH * 2);
    #pragma unroll 8
    for (int j = 0; j < CH; j += 2) {
        const int t = c * CH + j;
        const float4 d  = *(const float4*)(dyb + j * 2);
        const float4 T0 = Ttab[t];
        const float4 T1 = Ttab[t + 1];
        const float h0  = kcDT * x0;
        const float nx0 = fmaf(T0.x, x0, fmaf(kw, x1, T0.z * d.x));
        const float nx1 = fmaf(T0.y, x0, fmaf(kA, x1, T0.w * d.x));
        const float h1  = kcDT * nx0;
        const float mx0 = fmaf(T1.x, nx0, fmaf(kw, nx1, T1.z * d.z));
        const float mx1 = fmaf(T1.y, nx0, fmaf(kA, nx1, T1.w * d.z));
        *(float4*)(dyh + j * 2) = make_float4(h0, 0.f, h1, 0.f);
        x0 = mx0; x1 = mx1;
    }

    if (c == 63) {
        const float4 fin = *(const float4*)(ws + WS_F);
        float* os = out + b * 6;
        os[0] = x0;    os[1] = x1;
        os[2] = fin.x; os[3] = fin.y; os[4] = fin.z; os[5] = fin.w;
    }
}

extern "C" void kernel_launch(void* const* d_in, const int* in_sizes, int n_in,
                              void* d_out, int out_size, void* d_ws, size_t ws_size,
                              hipStream_t stream) {
    const float* dy     = (const float*)d_in[0];
    const float* state0 = (const float*)d_in[1];
    const float* omega  = (const float*)d_in[2];
    float* out = (float*)d_out;
    float* ws  = (float*)d_ws;
    grnn_phaseA<<<1, 64, 0, stream>>>(state0, omega, ws);
    grnn_phaseBCD<<<B, 64, 0, stream>>>(dy, state0, omega, out, ws);
}